// Round 1
// baseline (732.494 us; speedup 1.0000x reference)
//
#include <hip/hip_runtime.h>
#include <math.h>

#define BB 64
#define TT 512
#define W_IN 40
#define NPTS 9
#define CF 8
#define GH 32
#define HOUT 510   // T-2
#define WOUT 38    // W_IN-2
#define GIN 304    // WOUT*CF
#define G3 96      // 3*GH
#define ATT 32

// ---------------- stage 1: deform conv + input GEMM -> xp[t][b][g] ----------
// grid: HOUT*4 blocks, 256 threads; each block: one t, 16 batches.
__global__ __launch_bounds__(256) void k_dcn_gemm(
    const float* __restrict__ x, const float* __restrict__ p_w, const float* __restrict__ p_b,
    const float* __restrict__ dcn_w, const float* __restrict__ dcn_b,
    const float* __restrict__ w_ih, const float* __restrict__ b_ih,
    float* __restrict__ xp)
{
    __shared__ float pw_s[2 * NPTS * NPTS]; // 162
    __shared__ float pb_s[2 * NPTS];        // 18
    __shared__ float dw_s[CF * NPTS];       // 72
    __shared__ float db_s[CF];              // 8
    __shared__ float seq_s[16][GIN];        // 16 batches x 304 (19.5 KB)

    const int t   = blockIdx.x >> 2;
    const int bb  = blockIdx.x & 3;
    const int tid = threadIdx.x;

    if (tid < 162) pw_s[tid] = p_w[tid];
    if (tid < 18)  pb_s[tid] = p_b[tid];
    if (tid < 72)  dw_s[tid] = dcn_w[tid];
    if (tid < 8)   db_s[tid] = dcn_b[tid];
    __syncthreads();

    // ---- phase A: deform-conv, write seq rows into LDS ----
    for (int item = tid; item < 16 * WOUT; item += 256) {
        const int bl = item / WOUT;
        const int wi = item % WOUT;
        const int b  = bb * 16 + bl;
        const float* xb = x + (size_t)b * TT * W_IN;

        float patch[9];
        #pragma unroll
        for (int ky = 0; ky < 3; ++ky)
            #pragma unroll
            for (int kx = 0; kx < 3; ++kx)
                patch[ky * 3 + kx] = xb[(t + ky) * W_IN + wi + kx];

        float offs[18];
        #pragma unroll
        for (int n = 0; n < 18; ++n) {
            float a = pb_s[n];
            #pragma unroll
            for (int k = 0; k < 9; ++k) a += patch[k] * pw_s[n * 9 + k];
            offs[n] = a;
        }

        float samp[9];
        #pragma unroll
        for (int n = 0; n < 9; ++n) {
            float py = offs[n]     + (float)(n / 3 - 1) + (float)(t + 1);
            float px = offs[9 + n] + (float)(n % 3 - 1) + (float)(wi + 1);
            py = fminf(fmaxf(py, 0.f), (float)(TT - 1));
            px = fminf(fmaxf(px, 0.f), (float)(W_IN - 1));
            float fy = floorf(py), fx = floorf(px);
            int y0 = (int)fy, x0 = (int)fx;
            int y1 = min(y0 + 1, TT - 1), x1 = min(x0 + 1, W_IN - 1);
            float wy = py - fy, wx = px - fx;
            float g00 = xb[y0 * W_IN + x0], g01 = xb[y0 * W_IN + x1];
            float g10 = xb[y1 * W_IN + x0], g11 = xb[y1 * W_IN + x1];
            samp[n] = g00 * (1.f - wy) * (1.f - wx) + g01 * (1.f - wy) * wx
                    + g10 * wy * (1.f - wx) + g11 * wy * wx;
        }

        #pragma unroll
        for (int c = 0; c < CF; ++c) {
            float a = db_s[c];
            #pragma unroll
            for (int n = 0; n < 9; ++n) a += samp[n] * dw_s[c * 9 + n];
            seq_s[bl][wi * CF + c] = a;
        }
    }
    __syncthreads();

    // ---- phase B: xp[t][b][g] = b_ih[g] + seq . w_ih[g,:] ----
    for (int o = tid; o < 16 * G3; o += 256) {
        const int bl = o / G3;
        const int g  = o % G3;
        const float4* wrow = (const float4*)(w_ih + (size_t)g * GIN);
        const float4* srow = (const float4*)(&seq_s[bl][0]);
        float4 acc4 = {0.f, 0.f, 0.f, 0.f};
        #pragma unroll 4
        for (int i = 0; i < GIN / 4; ++i) {
            float4 wv = wrow[i], sv = srow[i];
            acc4.x += wv.x * sv.x; acc4.y += wv.y * sv.y;
            acc4.z += wv.z * sv.z; acc4.w += wv.w * sv.w;
        }
        const int b = bb * 16 + bl;
        xp[((size_t)t * BB + b) * G3 + g] =
            b_ih[g] + ((acc4.x + acc4.y) + (acc4.z + acc4.w));
    }
}

// ---------------- stage 2: GRU recurrence -----------------------------------
// grid: 32 blocks x 64 threads (1 wave). Wave handles 2 batches:
// lane = (g = lane>>5 batch-half, j = lane&31 hidden index).
__global__ __launch_bounds__(64) void k_gru(
    const float* __restrict__ xp, const float* __restrict__ w_hh,
    const float* __restrict__ b_hh, float* __restrict__ enc)
{
    const int lane = threadIdx.x;
    const int g = lane >> 5;
    const int j = lane & 31;
    const int b = blockIdx.x * 2 + g;

    float wr[GH], wz[GH], wn[GH];
    #pragma unroll
    for (int i = 0; i < GH; ++i) {
        wr[i] = w_hh[(size_t)(j) * GH + i];
        wz[i] = w_hh[(size_t)(GH + j) * GH + i];
        wn[i] = w_hh[(size_t)(2 * GH + j) * GH + i];
    }
    const float br = b_hh[j], bz = b_hh[GH + j], bn = b_hh[2 * GH + j];

    __shared__ float hsh[2][GH];
    hsh[g][j] = 0.f;
    float h = 0.f;
    __syncthreads();

    const float* xp0 = xp + (size_t)b * G3;
    float xr = xp0[j], xz = xp0[GH + j], xn = xp0[2 * GH + j];

    for (int t = 0; t < HOUT; ++t) {
        float nxr = 0.f, nxz = 0.f, nxn = 0.f;
        if (t + 1 < HOUT) {
            const float* xq = xp + ((size_t)(t + 1) * BB + b) * G3;
            nxr = xq[j]; nxz = xq[GH + j]; nxn = xq[2 * GH + j];
        }

        float ar = br, az = bz, an = bn;
        const float4* hv4 = (const float4*)(&hsh[g][0]);
        #pragma unroll
        for (int q = 0; q < GH / 4; ++q) {
            float4 hv = hv4[q];
            ar += wr[4*q+0]*hv.x + wr[4*q+1]*hv.y + wr[4*q+2]*hv.z + wr[4*q+3]*hv.w;
            az += wz[4*q+0]*hv.x + wz[4*q+1]*hv.y + wz[4*q+2]*hv.z + wz[4*q+3]*hv.w;
            an += wn[4*q+0]*hv.x + wn[4*q+1]*hv.y + wn[4*q+2]*hv.z + wn[4*q+3]*hv.w;
        }

        float rg = 1.f / (1.f + expf(-(xr + ar)));
        float zg = 1.f / (1.f + expf(-(xz + az)));
        float ng = tanhf(xn + rg * an);
        h = (1.f - zg) * ng + zg * h;

        enc[((size_t)b * HOUT + t) * GH + j] = h;

        __syncthreads();
        hsh[g][j] = h;
        __syncthreads();

        xr = nxr; xz = nxz; xn = nxn;
    }
}

// ---------------- stage 3: attention pool + head ----------------------------
// grid: 64 blocks (one per batch), 256 threads = 8 time-lanes x 32 features.
__global__ __launch_bounds__(256) void k_attn(
    const float* __restrict__ enc,
    const float* __restrict__ w1, const float* __restrict__ b1,
    const float* __restrict__ w2, const float* __restrict__ b2,
    const float* __restrict__ w3, const float* __restrict__ b3,
    float* __restrict__ out)
{
    __shared__ float w1s[ATT * 33], w2s[GH * 33];  // padded stride 33 (bank-conflict fix)
    __shared__ float b1s[ATT], b2s[GH];
    __shared__ float encs[8][GH], apres[8][ATT];
    __shared__ float rm[8 * GH], rs[8 * GH], rp[8 * GH];
    __shared__ float pooled[GH];

    const int b   = blockIdx.x;
    const int tid = threadIdx.x;
    const int ttl = tid >> 5;   // 0..7 time lane
    const int j   = tid & 31;

    for (int i = tid; i < ATT * GH; i += 256) {
        int r = i >> 5, c = i & 31;
        w1s[r * 33 + c] = w1[i];
        w2s[r * 33 + c] = w2[i];
    }
    if (tid < ATT)              b1s[tid] = b1[tid];
    else if (tid < ATT + GH)    b2s[tid - ATT] = b2[tid - ATT];
    __syncthreads();

    float m = -INFINITY, s = 0.f, p = 0.f;
    const float* encb = enc + (size_t)b * HOUT * GH;

    for (int t0 = 0; t0 < HOUT; t0 += 8) {
        const int t = t0 + ttl;
        const bool act = (t < HOUT);
        const float ev = act ? encb[t * GH + j] : 0.f;
        encs[ttl][j] = ev;
        __syncthreads();

        float a1 = b1s[j];
        #pragma unroll
        for (int k = 0; k < GH; ++k) a1 += encs[ttl][k] * w1s[j * 33 + k];
        apres[ttl][j] = tanhf(a1);
        __syncthreads();

        float a2 = b2s[j];
        #pragma unroll
        for (int k = 0; k < ATT; ++k) a2 += apres[ttl][k] * w2s[j * 33 + k];

        if (act) {
            float mn = fmaxf(m, a2);
            float sc = expf(m - mn);   // m = -inf first time -> 0
            float e  = expf(a2 - mn);
            s = s * sc + e;
            p = p * sc + e * ev;
            m = mn;
        }
        __syncthreads();
    }

    rm[tid] = m; rs[tid] = s; rp[tid] = p;
    __syncthreads();

    if (tid < GH) {
        float M = -INFINITY;
        #pragma unroll
        for (int q = 0; q < 8; ++q) M = fmaxf(M, rm[q * GH + tid]);
        float S = 0.f, P = 0.f;
        #pragma unroll
        for (int q = 0; q < 8; ++q) {
            float sc = expf(rm[q * GH + tid] - M);
            S += rs[q * GH + tid] * sc;
            P += rp[q * GH + tid] * sc;
        }
        pooled[tid] = P / S;
    }
    __syncthreads();

    if (tid < 2) {
        float a = b3[tid];
        #pragma unroll
        for (int k = 0; k < GH; ++k) a += pooled[k] * w3[tid * GH + k];
        out[b * 2 + tid] = a;
    }
}

extern "C" void kernel_launch(void* const* d_in, const int* in_sizes, int n_in,
                              void* d_out, int out_size, void* d_ws, size_t ws_size,
                              hipStream_t stream)
{
    const float* x     = (const float*)d_in[0];
    const float* p_w   = (const float*)d_in[1];
    const float* p_b   = (const float*)d_in[2];
    const float* dcn_w = (const float*)d_in[3];
    const float* dcn_b = (const float*)d_in[4];
    const float* w_ih  = (const float*)d_in[5];
    const float* w_hh  = (const float*)d_in[6];
    const float* b_ih  = (const float*)d_in[7];
    const float* b_hh  = (const float*)d_in[8];
    const float* w1    = (const float*)d_in[9];
    const float* b1    = (const float*)d_in[10];
    const float* w2    = (const float*)d_in[11];
    const float* b2    = (const float*)d_in[12];
    const float* w3    = (const float*)d_in[13];
    const float* b3    = (const float*)d_in[14];
    float* out = (float*)d_out;

    float* xp  = (float*)d_ws;                     // HOUT*BB*G3 = 3,133,440 f (12.5 MB)
    float* enc = xp + (size_t)HOUT * BB * G3;      // BB*HOUT*GH = 1,044,480 f (4.2 MB)

    hipLaunchKernelGGL(k_dcn_gemm, dim3(HOUT * 4), dim3(256), 0, stream,
                       x, p_w, p_b, dcn_w, dcn_b, w_ih, b_ih, xp);
    hipLaunchKernelGGL(k_gru, dim3(BB / 2), dim3(64), 0, stream,
                       xp, w_hh, b_hh, enc);
    hipLaunchKernelGGL(k_attn, dim3(BB), dim3(256), 0, stream,
                       enc, w1, b1, w2, b2, w3, b3, out);
}

// Round 4
// 464.854 us; speedup vs baseline: 1.5757x; 1.5757x over previous
//
#include <hip/hip_runtime.h>
#include <math.h>
#include <stdint.h>

#define BB 64
#define TT 512
#define W_IN 40
#define CF 8
#define GH 32
#define HOUT 510   // T-2
#define WOUT 38    // W_IN-2
#define GIN 304    // WOUT*CF
#define G3 96      // 3*GH
#define ATT 32
#define MROWS (HOUT * BB)   // 32640 = 255*128
#define KC2 152             // K-chunk = 19 wi * 8 ch
#define WI_C 19

#define LOG2E 1.4426950408889634f

__device__ __forceinline__ float fast_rcp(float x) {
#if defined(__has_builtin)
# if __has_builtin(__builtin_amdgcn_rcpf)
    return __builtin_amdgcn_rcpf(x);
# else
    return 1.f / x;
# endif
#else
    return 1.f / x;
#endif
}

__device__ __forceinline__ float fast_exp2(float x) {
#if defined(__has_builtin)
# if __has_builtin(__builtin_amdgcn_exp2f)
    return __builtin_amdgcn_exp2f(x);
# else
    return exp2f(x);
# endif
#else
    return exp2f(x);
#endif
}

typedef __attribute__((address_space(3))) uint32_t lds_u32_t;
typedef const __attribute__((address_space(1))) uint32_t glb_u32_t;

// ============ stage 1: fused deform-conv + input GEMM -> xp[t*64+b][96] =====
// 255 blocks x 192 threads. Block = rows [r0, r0+128), r = t*64+b, t in
// {2*bx, 2*bx+1}. Deform-conv writes A-tile straight to LDS (phase A);
// w_ih K-chunk staged via async global_load_lds overlapped with phase A;
// 8x8 register tiles on strided sets (mg+16i, ng+12j) -> <=2-way LDS
// conflicts (free per m136).
__global__ __launch_bounds__(192, 1) void k_dcn_gemm(
    const float* __restrict__ x, const float* __restrict__ p_w, const float* __restrict__ p_b,
    const float* __restrict__ dcn_w, const float* __restrict__ dcn_b,
    const float* __restrict__ w_ih, const float* __restrict__ b_ih,
    float* __restrict__ xp)
{
    __shared__ float As[128 * KC2];   // 77.8 KB
    __shared__ float Ws[96 * KC2];    // 58.4 KB
    __shared__ float pw_s[162], pb_s[18], dw_s[72], db_s[8];

    const int tid = threadIdx.x;
    const int t0  = blockIdx.x * 2;
    const int r0  = blockIdx.x * 128;
    const int mg  = tid / 12;   // 0..15
    const int ng  = tid % 12;   // 0..11

    if (tid < 162) pw_s[tid] = p_w[tid];
    if (tid < 18)  pb_s[tid] = p_b[tid];
    if (tid < 72)  dw_s[tid] = dcn_w[tid];
    if (tid < 8)   db_s[tid] = dcn_b[tid];

    float bih[8];
    #pragma unroll
    for (int j = 0; j < 8; ++j) bih[j] = b_ih[ng + 12 * j];

    float acc[8][8];
    #pragma unroll
    for (int i = 0; i < 8; ++i)
        #pragma unroll
        for (int j = 0; j < 8; ++j) acc[i][j] = 0.f;

    // stage W chunk ch (96 x 152 floats) into Ws: wave-uniform base + lane*16
    auto stageW = [&](int ch) {
        for (int u4 = tid; u4 < 96 * (KC2 / 4); u4 += 192) {   // 3648/192 = 19 exact
            const int g   = u4 / (KC2 / 4);
            const int k4l = u4 % (KC2 / 4);
            const float* src = w_ih + (size_t)g * GIN + ch * KC2 + k4l * 4;
            float* dst = &Ws[u4 * 4];
#if defined(__has_builtin) && __has_builtin(__builtin_amdgcn_global_load_lds)
            __builtin_amdgcn_global_load_lds((glb_u32_t*)(uintptr_t)src,
                                             (lds_u32_t*)(uintptr_t)dst, 16, 0, 0);
#else
            *(float4*)dst = *(const float4*)src;
#endif
        }
    };

    // phase A: deform-conv for wi in [ch*19, ch*19+19) -> As[lr][wl*8+c]
    auto phaseA = [&](int ch) {
        for (int item = tid; item < 128 * WI_C; item += 192) {
            const int lr = item / WI_C;       // 0..127 (t_local*64 + b)
            const int wl = item % WI_C;       // 0..18
            const int wi = ch * WI_C + wl;
            const int t  = t0 + (lr >> 6);
            const int b  = lr & 63;
            const float* xb = x + (size_t)b * TT * W_IN;

            float patch[9];
            #pragma unroll
            for (int ky = 0; ky < 3; ++ky)
                #pragma unroll
                for (int kx = 0; kx < 3; ++kx)
                    patch[ky * 3 + kx] = xb[(t + ky) * W_IN + wi + kx];

            float offs[18];
            #pragma unroll
            for (int n = 0; n < 18; ++n) {
                float a = pb_s[n];
                #pragma unroll
                for (int k = 0; k < 9; ++k) a += patch[k] * pw_s[n * 9 + k];
                offs[n] = a;
            }

            float samp[9];
            #pragma unroll
            for (int n = 0; n < 9; ++n) {
                float py = offs[n]     + (float)(n / 3 - 1) + (float)(t + 1);
                float px = offs[9 + n] + (float)(n % 3 - 1) + (float)(wi + 1);
                py = fminf(fmaxf(py, 0.f), (float)(TT - 1));
                px = fminf(fmaxf(px, 0.f), (float)(W_IN - 1));
                float fy = floorf(py), fx = floorf(px);
                int y0 = (int)fy, x0 = (int)fx;
                int y1 = min(y0 + 1, TT - 1), x1 = min(x0 + 1, W_IN - 1);
                float wy = py - fy, wx = px - fx;
                float g00 = xb[y0 * W_IN + x0], g01 = xb[y0 * W_IN + x1];
                float g10 = xb[y1 * W_IN + x0], g11 = xb[y1 * W_IN + x1];
                samp[n] = g00 * (1.f - wy) * (1.f - wx) + g01 * (1.f - wy) * wx
                        + g10 * wy * (1.f - wx) + g11 * wy * wx;
            }

            float o[CF];
            #pragma unroll
            for (int c = 0; c < CF; ++c) {
                float a = db_s[c];
                #pragma unroll
                for (int n = 0; n < 9; ++n) a += samp[n] * dw_s[c * 9 + n];
                o[c] = a;
            }
            float* arow = &As[lr * KC2 + wl * 8];
            ((float4*)arow)[0] = make_float4(o[0], o[1], o[2], o[3]);
            ((float4*)arow)[1] = make_float4(o[4], o[5], o[6], o[7]);
        }
    };

    auto gemm = [&]() {
        #pragma unroll 2
        for (int k4 = 0; k4 < KC2 / 4; ++k4) {
            float4 a[8], w[8];
            #pragma unroll
            for (int i = 0; i < 8; ++i)
                a[i] = *(const float4*)&As[(mg + 16 * i) * KC2 + k4 * 4];
            #pragma unroll
            for (int j = 0; j < 8; ++j)
                w[j] = *(const float4*)&Ws[(ng + 12 * j) * KC2 + k4 * 4];
            #pragma unroll
            for (int i = 0; i < 8; ++i)
                #pragma unroll
                for (int j = 0; j < 8; ++j)
                    acc[i][j] += a[i].x * w[j].x + a[i].y * w[j].y
                               + a[i].z * w[j].z + a[i].w * w[j].w;
        }
    };

    __syncthreads();          // params visible
    stageW(0);                // async, overlaps phase A
    phaseA(0);
    __syncthreads();          // Ws(0) + As(0) ready (barrier drains vmcnt)
    gemm();
    __syncthreads();          // done reading before overwrite
    stageW(1);
    phaseA(1);
    __syncthreads();
    gemm();

    #pragma unroll
    for (int i = 0; i < 8; ++i) {
        const int row = r0 + mg + 16 * i;
        #pragma unroll
        for (int j = 0; j < 8; ++j)
            xp[(size_t)row * G3 + ng + 12 * j] = acc[i][j] + bih[j];
    }
}

// ============ stage 2: GRU recurrence, 2 lanes per hidden unit ==============
// 64 blocks x 64 threads (1 wave = 1 batch). lane = (half, j): each half-wave
// does 16 of the 32 recurrent FMAs per gate; combine via shfl_xor(32).
// Barrier-free: h broadcast by __shfl, so enc stores / xp prefetches never
// force a vmcnt drain inside the recurrence.
__global__ __launch_bounds__(64) void k_gru(
    const float* __restrict__ xp, const float* __restrict__ w_hh,
    const float* __restrict__ b_hh, float* __restrict__ enc)
{
    const int l = threadIdx.x;
    const int half = l >> 5;
    const int j = l & 31;
    const int b = blockIdx.x;

    float wr[16], wz[16], wn[16];
    #pragma unroll
    for (int i = 0; i < 16; ++i) {
        wr[i] = w_hh[(size_t)j * GH + half * 16 + i];
        wz[i] = w_hh[(size_t)(GH + j) * GH + half * 16 + i];
        wn[i] = w_hh[(size_t)(2 * GH + j) * GH + half * 16 + i];
    }
    const float br = b_hh[j], bz = b_hh[GH + j], bn = b_hh[2 * GH + j];

    float h = 0.f;
    const float* xb = xp + (size_t)b * G3;   // row t=0
    float xr = xb[j], xz = xb[GH + j], xn = xb[2 * GH + j];

    for (int t = 0; t < HOUT; ++t) {
        const int tn = (t + 1 < HOUT) ? t + 1 : t;
        const float* xq = xp + ((size_t)tn * BB + b) * G3;
        float nxr = xq[j], nxz = xq[GH + j], nxn = xq[2 * GH + j];

        float pr = 0.f, pz = 0.f, pn = 0.f;
        #pragma unroll
        for (int i = 0; i < 16; ++i) {
            float hk = __shfl(h, half * 16 + i, 64);
            pr += wr[i] * hk; pz += wz[i] * hk; pn += wn[i] * hk;
        }
        float ar = br + pr + __shfl_xor(pr, 32, 64);
        float az = bz + pz + __shfl_xor(pz, 32, 64);
        float an = bn + pn + __shfl_xor(pn, 32, 64);

        float rg = fast_rcp(1.f + fast_exp2(-(xr + ar) * LOG2E));
        float zg = fast_rcp(1.f + fast_exp2(-(xz + az) * LOG2E));
        float pre = xn + rg * an;
        float e2 = fast_exp2(pre * (2.f * LOG2E));
        float tg = 1.f - 2.f * fast_rcp(e2 + 1.f);   // tanh(pre)
        h = (1.f - zg) * tg + zg * h;

        if (!half) enc[((size_t)b * HOUT + t) * GH + j] = h;
        xr = nxr; xz = nxz; xn = nxn;
    }
}

// ============ stage 3a: attention partials over time chunks =================
// grid 256 = 64 batches x 4 chunks of 128 timesteps; 256 thr = 8 t-lanes x 32.
__global__ __launch_bounds__(256) void k_attn_part(
    const float* __restrict__ enc,
    const float* __restrict__ w1, const float* __restrict__ b1,
    const float* __restrict__ w2, const float* __restrict__ b2,
    float* __restrict__ part)
{
    __shared__ float w1s[ATT * 33], w2s[GH * 33];   // stride-33 pad
    __shared__ float b1s[ATT], b2s[GH];
    __shared__ float encs[8][GH], apres[8][ATT];
    __shared__ float rm[8 * GH], rs[8 * GH], rp[8 * GH];

    const int b   = blockIdx.x >> 2;
    const int c   = blockIdx.x & 3;
    const int tid = threadIdx.x;
    const int ttl = tid >> 5;
    const int j   = tid & 31;

    for (int i = tid; i < ATT * GH; i += 256) {
        int r = i >> 5, cc = i & 31;
        w1s[r * 33 + cc] = w1[i];
        w2s[r * 33 + cc] = w2[i];
    }
    if (tid < ATT)           b1s[tid] = b1[tid];
    else if (tid < ATT + GH) b2s[tid - ATT] = b2[tid - ATT];
    __syncthreads();

    const int tbeg = c * 128;
    const int tend = min(HOUT, tbeg + 128);

    float m = -INFINITY, s = 0.f, p = 0.f;
    const float* encb = enc + (size_t)b * HOUT * GH;

    for (int t0 = tbeg; t0 < tend; t0 += 8) {
        const int t = t0 + ttl;
        const bool act = (t < tend);
        const float ev = act ? encb[t * GH + j] : 0.f;
        encs[ttl][j] = ev;
        __syncthreads();

        float a1 = b1s[j];
        #pragma unroll
        for (int k = 0; k < GH; ++k) a1 += encs[ttl][k] * w1s[j * 33 + k];
        apres[ttl][j] = tanhf(a1);
        __syncthreads();

        float a2 = b2s[j];
        #pragma unroll
        for (int k = 0; k < ATT; ++k) a2 += apres[ttl][k] * w2s[j * 33 + k];

        if (act) {
            float mn = fmaxf(m, a2);
            float sc = expf(m - mn);
            float e  = expf(a2 - mn);
            s = s * sc + e;
            p = p * sc + e * ev;
            m = mn;
        }
        __syncthreads();
    }

    rm[tid] = m; rs[tid] = s; rp[tid] = p;
    __syncthreads();

    if (tid < GH) {
        float M = -INFINITY;
        #pragma unroll
        for (int q = 0; q < 8; ++q) M = fmaxf(M, rm[q * GH + tid]);
        float S = 0.f, P = 0.f;
        #pragma unroll
        for (int q = 0; q < 8; ++q) {
            float sc = expf(rm[q * GH + tid] - M);
            S += rs[q * GH + tid] * sc;
            P += rp[q * GH + tid] * sc;
        }
        float* pb = part + ((size_t)b * 4 + c) * 96;
        pb[tid] = M; pb[32 + tid] = S; pb[64 + tid] = P;
    }
}

// ============ stage 3b: merge partials + head ===============================
__global__ __launch_bounds__(64) void k_attn_fin(
    const float* __restrict__ part,
    const float* __restrict__ w3, const float* __restrict__ b3,
    float* __restrict__ out)
{
    __shared__ float pooled[GH];
    const int b = blockIdx.x;
    const int tid = threadIdx.x;

    if (tid < GH) {
        const float* pb = part + (size_t)b * 4 * 96;
        float M = -INFINITY;
        #pragma unroll
        for (int c = 0; c < 4; ++c) M = fmaxf(M, pb[c * 96 + tid]);
        float S = 0.f, P = 0.f;
        #pragma unroll
        for (int c = 0; c < 4; ++c) {
            float sc = expf(pb[c * 96 + tid] - M);
            S += pb[c * 96 + 32 + tid] * sc;
            P += pb[c * 96 + 64 + tid] * sc;
        }
        pooled[tid] = P / S;
    }
    __syncthreads();

    if (tid < 2) {
        float a = b3[tid];
        #pragma unroll
        for (int k = 0; k < GH; ++k) a += pooled[k] * w3[tid * GH + k];
        out[b * 2 + tid] = a;
    }
}

extern "C" void kernel_launch(void* const* d_in, const int* in_sizes, int n_in,
                              void* d_out, int out_size, void* d_ws, size_t ws_size,
                              hipStream_t stream)
{
    const float* x     = (const float*)d_in[0];
    const float* p_w   = (const float*)d_in[1];
    const float* p_b   = (const float*)d_in[2];
    const float* dcn_w = (const float*)d_in[3];
    const float* dcn_b = (const float*)d_in[4];
    const float* w_ih  = (const float*)d_in[5];
    const float* w_hh  = (const float*)d_in[6];
    const float* b_ih  = (const float*)d_in[7];
    const float* b_hh  = (const float*)d_in[8];
    const float* w1    = (const float*)d_in[9];
    const float* b1    = (const float*)d_in[10];
    const float* w2    = (const float*)d_in[11];
    const float* b2    = (const float*)d_in[12];
    const float* w3    = (const float*)d_in[13];
    const float* b3    = (const float*)d_in[14];
    float* out = (float*)d_out;

    // ws: xp 12.5 MB | enc 4.2 MB  (total 16.74 MB, exactly round-1-proven).
    // part (96 KB) aliases the head of xp: xp is dead once k_gru completes,
    // and k_attn_part launches after k_gru on the same stream.
    float* xp   = (float*)d_ws;                      // MROWS*G3
    float* enc  = xp + (size_t)MROWS * G3;           // BB*HOUT*GH
    float* part = xp;                                // 64*4*96 floats

    hipLaunchKernelGGL(k_dcn_gemm, dim3(MROWS / 128), dim3(192), 0, stream,
                       x, p_w, p_b, dcn_w, dcn_b, w_ih, b_ih, xp);
    hipLaunchKernelGGL(k_gru, dim3(BB), dim3(64), 0, stream,
                       xp, w_hh, b_hh, enc);
    hipLaunchKernelGGL(k_attn_part, dim3(BB * 4), dim3(256), 0, stream,
                       enc, w1, b1, w2, b2, part);
    hipLaunchKernelGGL(k_attn_fin, dim3(BB), dim3(64), 0, stream,
                       part, w3, b3, out);
}

// Round 9
// 380.380 us; speedup vs baseline: 1.9257x; 1.2221x over previous
//
#include <hip/hip_runtime.h>
#include <math.h>
#include <stdint.h>

#define BB 64
#define TT 512
#define W_IN 40
#define CF 8
#define GH 32
#define HOUT 510   // T-2
#define WOUT 38    // W_IN-2
#define GIN 304    // WOUT*CF
#define G3 96      // 3*GH
#define ATT 32
#define MROWS (HOUT * BB)   // 32640 = 255*128

#define LOG2E 1.4426950408889634f

__device__ __forceinline__ float fast_rcp(float x) {
#if defined(__has_builtin)
# if __has_builtin(__builtin_amdgcn_rcpf)
    return __builtin_amdgcn_rcpf(x);
# else
    return 1.f / x;
# endif
#else
    return 1.f / x;
#endif
}

__device__ __forceinline__ float fast_exp2(float x) {
#if defined(__has_builtin)
# if __has_builtin(__builtin_amdgcn_exp2f)
    return __builtin_amdgcn_exp2f(x);
# else
    return exp2f(x);
# endif
#else
    return exp2f(x);
#endif
}

typedef __attribute__((address_space(3))) uint32_t lds_u32_t;
typedef const __attribute__((address_space(1))) uint32_t glb_u32_t;

#if defined(__has_builtin) && __has_builtin(__builtin_amdgcn_global_load_lds)
#define HAS_GLL 1
#else
#define HAS_GLL 0
#endif

// ============ stage 1: fused deform-conv + input GEMM (round-4 PROVEN) ======
// 255 blocks x 192 threads. Block = rows [r0, r0+128), r = t*64+b, t in
// {2*bx, 2*bx+1}. Deform-conv writes A-tile straight to LDS (phase A);
// w_ih K-chunk staged via async global_load_lds overlapped with phase A;
// 8x8 register tiles on strided sets (mg+16i, ng+12j).
#define KC2 152
#define WI_C 19
__global__ __launch_bounds__(192, 1) void k_dcn_gemm_fused(
    const float* __restrict__ x, const float* __restrict__ p_w, const float* __restrict__ p_b,
    const float* __restrict__ dcn_w, const float* __restrict__ dcn_b,
    const float* __restrict__ w_ih, const float* __restrict__ b_ih,
    float* __restrict__ xp)
{
    __shared__ float As[128 * KC2];   // 77.8 KB
    __shared__ float Ws[96 * KC2];    // 58.4 KB
    __shared__ float pw_s[162], pb_s[18], dw_s[72], db_s[8];

    const int tid = threadIdx.x;
    const int t0  = blockIdx.x * 2;
    const int r0  = blockIdx.x * 128;
    const int mg  = tid / 12;
    const int ng  = tid % 12;

    if (tid < 162) pw_s[tid] = p_w[tid];
    if (tid < 18)  pb_s[tid] = p_b[tid];
    if (tid < 72)  dw_s[tid] = dcn_w[tid];
    if (tid < 8)   db_s[tid] = dcn_b[tid];

    float bih[8];
    #pragma unroll
    for (int j = 0; j < 8; ++j) bih[j] = b_ih[ng + 12 * j];

    float acc[8][8];
    #pragma unroll
    for (int i = 0; i < 8; ++i)
        #pragma unroll
        for (int j = 0; j < 8; ++j) acc[i][j] = 0.f;

    auto stageW = [&](int ch) {
        for (int u4 = tid; u4 < 96 * (KC2 / 4); u4 += 192) {   // 3648/192=19 exact
            const int g   = u4 / (KC2 / 4);
            const int k4l = u4 % (KC2 / 4);
            const float* src = w_ih + (size_t)g * GIN + ch * KC2 + k4l * 4;
            float* dst = &Ws[u4 * 4];
#if HAS_GLL
            __builtin_amdgcn_global_load_lds((glb_u32_t*)(uintptr_t)src,
                                             (lds_u32_t*)(uintptr_t)dst, 16, 0, 0);
#else
            *(float4*)dst = *(const float4*)src;
#endif
        }
    };

    auto phaseA = [&](int ch) {
        for (int item = tid; item < 128 * WI_C; item += 192) {
            const int lr = item / WI_C;
            const int wl = item % WI_C;
            const int wi = ch * WI_C + wl;
            const int t  = t0 + (lr >> 6);
            const int b  = lr & 63;
            const float* xb = x + (size_t)b * TT * W_IN;

            float patch[9];
            #pragma unroll
            for (int ky = 0; ky < 3; ++ky)
                #pragma unroll
                for (int kx = 0; kx < 3; ++kx)
                    patch[ky * 3 + kx] = xb[(t + ky) * W_IN + wi + kx];

            float offs[18];
            #pragma unroll
            for (int n = 0; n < 18; ++n) {
                float a = pb_s[n];
                #pragma unroll
                for (int k = 0; k < 9; ++k) a += patch[k] * pw_s[n * 9 + k];
                offs[n] = a;
            }

            float samp[9];
            #pragma unroll
            for (int n = 0; n < 9; ++n) {
                float py = offs[n]     + (float)(n / 3 - 1) + (float)(t + 1);
                float px = offs[9 + n] + (float)(n % 3 - 1) + (float)(wi + 1);
                py = fminf(fmaxf(py, 0.f), (float)(TT - 1));
                px = fminf(fmaxf(px, 0.f), (float)(W_IN - 1));
                float fy = floorf(py), fx = floorf(px);
                int y0 = (int)fy, x0 = (int)fx;
                int y1 = min(y0 + 1, TT - 1), x1 = min(x0 + 1, W_IN - 1);
                float wy = py - fy, wx = px - fx;
                float g00 = xb[y0 * W_IN + x0], g01 = xb[y0 * W_IN + x1];
                float g10 = xb[y1 * W_IN + x0], g11 = xb[y1 * W_IN + x1];
                samp[n] = g00 * (1.f - wy) * (1.f - wx) + g01 * (1.f - wy) * wx
                        + g10 * wy * (1.f - wx) + g11 * wy * wx;
            }

            float o[CF];
            #pragma unroll
            for (int c = 0; c < CF; ++c) {
                float a = db_s[c];
                #pragma unroll
                for (int n = 0; n < 9; ++n) a += samp[n] * dw_s[c * 9 + n];
                o[c] = a;
            }
            float* arow = &As[lr * KC2 + wl * 8];
            ((float4*)arow)[0] = make_float4(o[0], o[1], o[2], o[3]);
            ((float4*)arow)[1] = make_float4(o[4], o[5], o[6], o[7]);
        }
    };

    auto gemm = [&]() {
        #pragma unroll 2
        for (int k4 = 0; k4 < KC2 / 4; ++k4) {
            float4 a[8], w[8];
            #pragma unroll
            for (int i = 0; i < 8; ++i)
                a[i] = *(const float4*)&As[(mg + 16 * i) * KC2 + k4 * 4];
            #pragma unroll
            for (int j = 0; j < 8; ++j)
                w[j] = *(const float4*)&Ws[(ng + 12 * j) * KC2 + k4 * 4];
            #pragma unroll
            for (int i = 0; i < 8; ++i)
                #pragma unroll
                for (int j = 0; j < 8; ++j)
                    acc[i][j] += a[i].x * w[j].x + a[i].y * w[j].y
                               + a[i].z * w[j].z + a[i].w * w[j].w;
        }
    };

    __syncthreads();          // params visible
    stageW(0);                // async, overlaps phase A
    phaseA(0);
    __syncthreads();          // Ws(0)+As(0) ready (barrier drains vmcnt)
    gemm();
    __syncthreads();          // readers done before overwrite
    stageW(1);
    phaseA(1);
    __syncthreads();
    gemm();

    #pragma unroll
    for (int i = 0; i < 8; ++i) {
        const int row = r0 + mg + 16 * i;
        #pragma unroll
        for (int j = 0; j < 8; ++j)
            xp[(size_t)row * G3 + ng + 12 * j] = acc[i][j] + bih[j];
    }
}

// ============ stage 2: GRU, LDS-chunk-staged x (THE EXPERIMENT) =============
// 64 blocks x 64 thr (1 wave = 1 batch). x-parts staged 16 steps at a time
// into LDS via global_load_lds, double-buffered, counted vmcnt(6): at the
// wait, the 6 newest outstanding VMEM ops are exactly chunk c+1's loads, so
// chunk c's loads AND all older enc stores have retired. HBM/L3 latency
// amortized over 16 steps. Recurrent dot split across half-waves (16
// FMA/gate/lane, 4-way acc trees), combined with shfl_xor(32). Barrier-free.
#define GCH 16
#define NCH 32      // 32*16 = 512 >= HOUT

__global__ __launch_bounds__(64) void k_gru(
    const float* __restrict__ xp, const float* __restrict__ w_hh,
    const float* __restrict__ b_hh, float* __restrict__ enc)
{
    __shared__ float xs[2][GCH * G3];   // 12 KB

    const int l = threadIdx.x;
    const int half = l >> 5;
    const int j = l & 31;
    const int b = blockIdx.x;

    float wr[16], wz[16], wn[16];
    #pragma unroll
    for (int i = 0; i < 16; ++i) {
        wr[i] = w_hh[(size_t)j * GH + half * 16 + i];
        wz[i] = w_hh[(size_t)(GH + j) * GH + half * 16 + i];
        wn[i] = w_hh[(size_t)(2 * GH + j) * GH + half * 16 + i];
    }
    const float br = b_hh[j], bz = b_hh[GH + j], bn = b_hh[2 * GH + j];

    // stage chunk c (16 steps x 96 floats = 6 issues x 64 lanes x 16B)
    auto stage = [&](int c, int buf) {
        #pragma unroll
        for (int k = 0; k < 6; ++k) {
            const int f  = k * 256 + l * 4;       // element index in chunk
            const int tl = f / 96;
            const int g  = f % 96;                // %4==0 -> 16B-aligned src
            int gt = c * GCH + tl;
            if (gt > HOUT - 1) gt = HOUT - 1;     // clamp (slots unused)
            const float* src = xp + ((size_t)gt * BB + b) * G3 + g;
            float* dst = &xs[buf][k * 256];       // wave-uniform base + lane*16B
#if HAS_GLL
            __builtin_amdgcn_global_load_lds((glb_u32_t*)(uintptr_t)src,
                                             (lds_u32_t*)(uintptr_t)dst, 16, 0, 0);
#else
            *(float4*)(&xs[buf][f]) = *(const float4*)src;
#endif
        }
    };

    stage(0, 0);
    float h = 0.f;

    #pragma unroll 1
    for (int c = 0; c < NCH; ++c) {
        const int buf = c & 1;
        if (c + 1 < NCH) {
            stage(c + 1, buf ^ 1);
            asm volatile("s_waitcnt vmcnt(6)" ::: "memory");
        } else {
            asm volatile("s_waitcnt vmcnt(0)" ::: "memory");
        }
        const int nst = (c == NCH - 1) ? (HOUT - (NCH - 1) * GCH) : GCH;
        #pragma unroll 1
        for (int tl = 0; tl < nst; ++tl) {
            const float* xrow = &xs[buf][tl * G3];
            const float xr = xrow[j], xz = xrow[GH + j], xn = xrow[2 * GH + j];

            float pr0 = 0.f, pr1 = 0.f, pr2 = 0.f, pr3 = 0.f;
            float pz0 = 0.f, pz1 = 0.f, pz2 = 0.f, pz3 = 0.f;
            float pn0 = 0.f, pn1 = 0.f, pn2 = 0.f, pn3 = 0.f;
            #pragma unroll
            for (int i = 0; i < 16; i += 4) {
                const float h0 = __shfl(h, half * 16 + i + 0, 64);
                const float h1 = __shfl(h, half * 16 + i + 1, 64);
                const float h2 = __shfl(h, half * 16 + i + 2, 64);
                const float h3 = __shfl(h, half * 16 + i + 3, 64);
                pr0 += wr[i + 0] * h0; pr1 += wr[i + 1] * h1;
                pr2 += wr[i + 2] * h2; pr3 += wr[i + 3] * h3;
                pz0 += wz[i + 0] * h0; pz1 += wz[i + 1] * h1;
                pz2 += wz[i + 2] * h2; pz3 += wz[i + 3] * h3;
                pn0 += wn[i + 0] * h0; pn1 += wn[i + 1] * h1;
                pn2 += wn[i + 2] * h2; pn3 += wn[i + 3] * h3;
            }
            const float pr = (pr0 + pr1) + (pr2 + pr3);
            const float pz = (pz0 + pz1) + (pz2 + pz3);
            const float pn = (pn0 + pn1) + (pn2 + pn3);
            const float ar = br + pr + __shfl_xor(pr, 32, 64);
            const float az = bz + pz + __shfl_xor(pz, 32, 64);
            const float an = bn + pn + __shfl_xor(pn, 32, 64);

            const float rg = fast_rcp(1.f + fast_exp2(-(xr + ar) * LOG2E));
            const float zg = fast_rcp(1.f + fast_exp2(-(xz + az) * LOG2E));
            const float pre = xn + rg * an;
            const float e2 = fast_exp2(pre * (2.f * LOG2E));
            const float tg = 1.f - 2.f * fast_rcp(e2 + 1.f);   // tanh(pre)
            h = (1.f - zg) * tg + zg * h;

            const int t = c * GCH + tl;
            if (!half) enc[((size_t)b * HOUT + t) * GH + j] = h;
        }
    }
}

// ============ stage 3a: attention partials (round-4 proven) =================
__global__ __launch_bounds__(256) void k_attn_part(
    const float* __restrict__ enc,
    const float* __restrict__ w1, const float* __restrict__ b1,
    const float* __restrict__ w2, const float* __restrict__ b2,
    float* __restrict__ part)
{
    __shared__ float w1s[ATT * 33], w2s[GH * 33];
    __shared__ float b1s[ATT], b2s[GH];
    __shared__ float encs[8][GH], apres[8][ATT];
    __shared__ float rm[8 * GH], rs[8 * GH], rp[8 * GH];

    const int b   = blockIdx.x >> 2;
    const int c   = blockIdx.x & 3;
    const int tid = threadIdx.x;
    const int ttl = tid >> 5;
    const int j   = tid & 31;

    for (int i = tid; i < ATT * GH; i += 256) {
        int r = i >> 5, cc = i & 31;
        w1s[r * 33 + cc] = w1[i];
        w2s[r * 33 + cc] = w2[i];
    }
    if (tid < ATT)           b1s[tid] = b1[tid];
    else if (tid < ATT + GH) b2s[tid - ATT] = b2[tid - ATT];
    __syncthreads();

    const int tbeg = c * 128;
    const int tend = min(HOUT, tbeg + 128);

    float m = -INFINITY, s = 0.f, p = 0.f;
    const float* encb = enc + (size_t)b * HOUT * GH;

    for (int t0 = tbeg; t0 < tend; t0 += 8) {
        const int t = t0 + ttl;
        const bool act = (t < tend);
        const float ev = act ? encb[t * GH + j] : 0.f;
        encs[ttl][j] = ev;
        __syncthreads();

        float a1 = b1s[j];
        #pragma unroll
        for (int k = 0; k < GH; ++k) a1 += encs[ttl][k] * w1s[j * 33 + k];
        apres[ttl][j] = tanhf(a1);
        __syncthreads();

        float a2 = b2s[j];
        #pragma unroll
        for (int k = 0; k < ATT; ++k) a2 += apres[ttl][k] * w2s[j * 33 + k];

        if (act) {
            float mn = fmaxf(m, a2);
            float sc = expf(m - mn);
            float e  = expf(a2 - mn);
            s = s * sc + e;
            p = p * sc + e * ev;
            m = mn;
        }
        __syncthreads();
    }

    rm[tid] = m; rs[tid] = s; rp[tid] = p;
    __syncthreads();

    if (tid < GH) {
        float M = -INFINITY;
        #pragma unroll
        for (int q = 0; q < 8; ++q) M = fmaxf(M, rm[q * GH + tid]);
        float S = 0.f, P = 0.f;
        #pragma unroll
        for (int q = 0; q < 8; ++q) {
            float sc = expf(rm[q * GH + tid] - M);
            S += rs[q * GH + tid] * sc;
            P += rp[q * GH + tid] * sc;
        }
        float* pb = part + ((size_t)b * 4 + c) * 96;
        pb[tid] = M; pb[32 + tid] = S; pb[64 + tid] = P;
    }
}

// ============ stage 3b: merge + head (round-4 proven) =======================
__global__ __launch_bounds__(64) void k_attn_fin(
    const float* __restrict__ part,
    const float* __restrict__ w3, const float* __restrict__ b3,
    float* __restrict__ out)
{
    __shared__ float pooled[GH];
    const int b = blockIdx.x;
    const int tid = threadIdx.x;

    if (tid < GH) {
        const float* pb = part + (size_t)b * 4 * 96;
        float M = -INFINITY;
        #pragma unroll
        for (int c = 0; c < 4; ++c) M = fmaxf(M, pb[c * 96 + tid]);
        float S = 0.f, P = 0.f;
        #pragma unroll
        for (int c = 0; c < 4; ++c) {
            float sc = expf(pb[c * 96 + tid] - M);
            S += pb[c * 96 + 32 + tid] * sc;
            P += pb[c * 96 + 64 + tid] * sc;
        }
        pooled[tid] = P / S;
    }
    __syncthreads();

    if (tid < 2) {
        float a = b3[tid];
        #pragma unroll
        for (int k = 0; k < GH; ++k) a += pooled[k] * w3[tid * GH + k];
        out[b * 2 + tid] = a;
    }
}

extern "C" void kernel_launch(void* const* d_in, const int* in_sizes, int n_in,
                              void* d_out, int out_size, void* d_ws, size_t ws_size,
                              hipStream_t stream)
{
    const float* x     = (const float*)d_in[0];
    const float* p_w   = (const float*)d_in[1];
    const float* p_b   = (const float*)d_in[2];
    const float* dcn_w = (const float*)d_in[3];
    const float* dcn_b = (const float*)d_in[4];
    const float* w_ih  = (const float*)d_in[5];
    const float* w_hh  = (const float*)d_in[6];
    const float* b_ih  = (const float*)d_in[7];
    const float* b_hh  = (const float*)d_in[8];
    const float* w1    = (const float*)d_in[9];
    const float* b1    = (const float*)d_in[10];
    const float* w2    = (const float*)d_in[11];
    const float* b2    = (const float*)d_in[12];
    const float* w3    = (const float*)d_in[13];
    const float* b3    = (const float*)d_in[14];
    float* out = (float*)d_out;

    // ws: xp 12.5 MB | enc 4.2 MB (16.74 MB total, round-4-proven).
    // part (96 KB) aliases the head of xp: xp is dead once k_gru completes,
    // and k_attn_part launches after k_gru on the same stream.
    const size_t XP_F = (size_t)MROWS * G3;
    float* xp   = (float*)d_ws;
    float* enc  = xp + XP_F;
    float* part = xp;

    hipLaunchKernelGGL(k_dcn_gemm_fused, dim3(MROWS / 128), dim3(192), 0, stream,
                       x, p_w, p_b, dcn_w, dcn_b, w_ih, b_ih, xp);
    hipLaunchKernelGGL(k_gru, dim3(BB), dim3(64), 0, stream,
                       xp, w_hh, b_hh, enc);
    hipLaunchKernelGGL(k_attn_part, dim3(BB * 4), dim3(256), 0, stream,
                       enc, w1, b1, w2, b2, part);
    hipLaunchKernelGGL(k_attn_fin, dim3(BB), dim3(64), 0, stream,
                       part, w3, b3, out);
}